// Round 8
// baseline (291.929 us; speedup 1.0000x reference)
//
#include <hip/hip_runtime.h>
#include <stdint.h>

#define BB 4096
#define TT 512
#define HH 32
#define SS 4

typedef float v2f __attribute__((ext_vector_type(2)));

__device__ __forceinline__ float fast_sigm(float a) {
  return __builtin_amdgcn_rcpf(1.0f + __expf(-a));      // v_exp + v_rcp
}
__device__ __forceinline__ float fast_tanh(float y) {
  return 1.0f - 2.0f * __builtin_amdgcn_rcpf(__expf(2.0f * y) + 1.0f);
}
// packed 2xf32 FMA (VOP3P): c = a*b + c elementwise
__device__ __forceinline__ v2f pkfma(v2f a, v2f b, v2f c) {
  asm("v_pk_fma_f32 %0, %1, %2, %0" : "+v"(c) : "v"(a), "v"(b));
  return c;
}

// 32 lanes per batch (lane j owns h[j]), 2 batches/wave, 4 waves/block.
// amdgpu_waves_per_eu(2,2) clamps the register-allocator occupancy target to
// exactly 2 waves/SIMD -> 256-VGPR budget -> the ~176-reg working set (96 w_hh
// + frags + h2) stays VGPR-resident instead of being spilled/sunk (rounds 4-7
// all failed to get residency because launch_bounds' waves-per-eu is only a
// MINIMUM and the heuristic aimed for 8 waves/EU = 64 VGPRs).
__global__ void __attribute__((amdgpu_flat_work_group_size(256, 256)))
__attribute__((amdgpu_waves_per_eu(2, 2))) gru_kernel(
    const float* __restrict__ x, const float* __restrict__ h0,
    const float* __restrict__ w_ih, const float* __restrict__ w_hh,
    const float* __restrict__ b_ih, const float* __restrict__ b_hh,
    const float* __restrict__ w_proj, const float* __restrict__ b_proj,
    float* __restrict__ out) {
  const int tid  = threadIdx.x;
  const int wid  = tid >> 6;        // wave in block 0..3
  const int lane = tid & 63;
  const int g    = lane >> 5;       // which batch of the wave's two
  const int j    = lane & 31;       // h index owned by this lane
  const int row  = wid * 2 + g;     // LDS row 0..7
  const int b    = blockIdx.x * 8 + row;

  __shared__ float lds_h[8][36];    // 144B row stride (conflict-free, r5)
  float* lrow = &lds_h[row][0];

  const int s_idx = j & 3;          // proj channel this lane reduces
  const int c_idx = j >> 2;         // h-chunk (of 8) this lane covers

  // ---- plain compiler-visible preload (allocator keeps it resident now) ----
  const float4* whh4 = (const float4*)w_hh;      // [96][8] float4
  v2f wr2[16], wz2[16], wn2[16];
#pragma unroll
  for (int c = 0; c < 8; ++c) {
    float4 a  = whh4[(0 * HH + j) * 8 + c];
    float4 bq = whh4[(1 * HH + j) * 8 + c];
    float4 cq = whh4[(2 * HH + j) * 8 + c];
    wr2[2*c] = (v2f){a.x,  a.y};  wr2[2*c+1] = (v2f){a.z,  a.w};
    wz2[2*c] = (v2f){bq.x, bq.y}; wz2[2*c+1] = (v2f){bq.z, bq.w};
    wn2[2*c] = (v2f){cq.x, cq.y}; wn2[2*c+1] = (v2f){cq.z, cq.w};
  }
  const float4* wih4 = (const float4*)w_ih;      // row = one float4 (I=4)
  const float4 wih_r = wih4[0 * HH + j];
  const float4 wih_z = wih4[1 * HH + j];
  const float4 wih_n = wih4[2 * HH + j];
  const float bir = b_ih[0*HH + j], biz = b_ih[1*HH + j], bin_ = b_ih[2*HH + j];
  const float bhr = b_hh[0*HH + j], bhz = b_hh[1*HH + j], bhn = b_hh[2*HH + j];

  const float4* wp4 = (const float4*)w_proj;     // [4][8] float4
  const float4 wp = wp4[s_idx * 8 + c_idx];
  const float bp = b_proj[s_idx];

  float h_self = h0[(size_t)b * HH + j];
  lrow[j] = h_self;

  const float4* xp = (const float4*)(x + (size_t)b * TT * 4);  // 512 float4
  float* outp = out + (size_t)b * TT * SS;
  const float* hc_addr = lrow + (c_idx << 2);

  float4 xv = xp[0];

  for (int t = 0; t <= TT; ++t) {
    // broadcast-read h_{t-1}: 8x b128 (2 distinct addrs/wave) + proj chunk
    v2f h2[16];
#pragma unroll
    for (int c = 0; c < 8; ++c) {
      const float4 q = *(const float4*)(lrow + 4 * c);
      h2[2*c] = (v2f){q.x, q.y}; h2[2*c+1] = (v2f){q.z, q.w};
    }
    const float4 hcv = *(const float4*)hc_addr;

    // deferred projection: out[t-1] = proj(h_{t-1})
    if (t > 0) {
      float v = fmaf(wp.x, hcv.x, fmaf(wp.y, hcv.y,
                fmaf(wp.z, hcv.z, wp.w * hcv.w)));
      v += __shfl_xor(v, 4, 64);
      v += __shfl_xor(v, 8, 64);
      v += __shfl_xor(v, 16, 64);
      if (c_idx == 0) {
        outp[(t - 1) * SS + s_idx] = v + bp;
      }
    }
    if (t == TT) break;

    float4 xvn = xp[(t + 1 < TT) ? (t + 1) : t];   // next-step x prefetch

    // input-gate contributions (I=4)
    float xr = fmaf(wih_r.x, xv.x, fmaf(wih_r.y, xv.y, fmaf(wih_r.z, xv.z, fmaf(wih_r.w, xv.w, bir))));
    float xz = fmaf(wih_z.x, xv.x, fmaf(wih_z.y, xv.y, fmaf(wih_z.z, xv.z, fmaf(wih_z.w, xv.w, biz))));
    float xn = fmaf(wih_n.x, xv.x, fmaf(wih_n.y, xv.y, fmaf(wih_n.z, xv.z, fmaf(wih_n.w, xv.w, bin_))));

    // hidden-gate contributions: 48 packed FMAs, bias folded into init
    v2f aR = (v2f){bhr, 0.f}, aZ = (v2f){bhz, 0.f}, aN = (v2f){bhn, 0.f};
#pragma unroll
    for (int m = 0; m < 16; ++m) {
      aR = pkfma(wr2[m], h2[m], aR);
      aZ = pkfma(wz2[m], h2[m], aZ);
      aN = pkfma(wn2[m], h2[m], aN);
    }
    const float hr = aR.x + aR.y;
    const float hz = aZ.x + aZ.y;
    const float hn = aN.x + aN.y;

    const float r  = fast_sigm(xr + hr);
    const float zz = fast_sigm(xz + hz);
    const float nn = fast_tanh(fmaf(r, hn, xn));
    const float hnew = fmaf(zz, h_self - nn, nn);  // (1-z)n + z h
    h_self = hnew;

    lrow[j] = hnew;   // publish h_t (same-wave, in-order DS pipe)

    xv = xvn;
  }

  // hn output: [1, B, H] appended after state (float32)
  out[(size_t)BB * TT * SS + (size_t)b * HH + j] = h_self;
}

extern "C" void kernel_launch(void* const* d_in, const int* in_sizes, int n_in,
                              void* d_out, int out_size, void* d_ws, size_t ws_size,
                              hipStream_t stream) {
  const float* x      = (const float*)d_in[0];
  const float* h0     = (const float*)d_in[1];
  const float* w_ih   = (const float*)d_in[2];
  const float* w_hh   = (const float*)d_in[3];
  const float* b_ih   = (const float*)d_in[4];
  const float* b_hh   = (const float*)d_in[5];
  const float* w_proj = (const float*)d_in[6];
  const float* b_proj = (const float*)d_in[7];
  float* out = (float*)d_out;

  dim3 grid(BB / 8), block(256);
  hipLaunchKernelGGL(gru_kernel, grid, block, 0, stream,
                     x, h0, w_ih, w_hh, b_ih, b_hh, w_proj, b_proj, out);
}